// Round 6
// baseline (174.428 us; speedup 1.0000x reference)
//
#include <hip/hip_runtime.h>
#include <hip/hip_bf16.h>

// SegmentDeactivation: KAN layer folded into one bf16 GEMM.
// K = 512*36 (dense-ified 4-sparse cubic B-spline bases) + 512 (silu(x)·W_base)
//   + 512 (x·masked-slope) = 19456 = 19*1024. bias = sum of masked intercepts.
// R6: thread-owned A-build (zero+scatter same thread -> 2 barriers/iter),
//     SPLITS=19 (KIT=16, partials halve), detect+pack_basis merged dispatch.

typedef unsigned short u16;
typedef unsigned int u32;
typedef unsigned long long u64;
typedef __attribute__((ext_vector_type(8))) short short8;
typedef __attribute__((ext_vector_type(4))) float floatx4;
typedef __attribute__((ext_vector_type(4))) unsigned int uintx4;

#define IN_F 512
#define OUT_F 512
#define BATCH 1024
#define K_SPLINE (IN_F * 36)            // 18432
#define K_BASE_OFF K_SPLINE
#define K_LIN_OFF (K_SPLINE + IN_F)
#define K_TOT (K_SPLINE + 2 * IN_F)     // 19456 = 19*1024
#define SPLITS 19
#define KPS 1024
#define KIT 16                          // KPS/64
#define MN (BATCH * OUT_F)

static __device__ inline u16 f2b(float f) {
  union { float f; u32 u; } v; v.f = f;
  u32 r = v.u + 0x7FFFu + ((v.u >> 16) & 1u);  // round-nearest-even
  return (u16)(r >> 16);
}

// ---- merged pre-pass: blocks <2048 precompute per-(b,i) basis into PB;
//      blocks >=2048 detect mask dtype (int32 / uint8-bool flags&1 / f32 flags&2)
__global__ __launch_bounds__(256) void pre_kernel(const float* __restrict__ x,
                                                  uintx4* __restrict__ PB,
                                                  const u32* __restrict__ maskw,
                                                  int* __restrict__ flags) {
  int blk = blockIdx.x, t = threadIdx.x;
  if (blk < 2048) {
    int id = blk * 256 + t;                  // i*1024 + b
    int i = id >> 10, b = id & 1023;
    float xv = x[(size_t)b * IN_F + i];

    int mc = (int)floorf((xv + 1.1875f) * 16.0f);
    float gm = (float)mc * 0.0625f - 1.1875f;
    if (xv < gm) { mc -= 1; gm -= 0.0625f; }
    else if (xv >= gm + 0.0625f) { mc += 1; gm += 0.0625f; }

    u16 r0 = 0, r1 = 0, r2 = 0, r3 = 0;
    if (mc >= 0 && mc <= 37) {
      float t_ = (xv - gm) * 16.0f;
      float t2 = t_ * t_, t3 = t2 * t_;
      float omt = 1.0f - t_;
      r0 = f2b(omt * omt * omt * (1.0f / 6.0f));
      r1 = f2b((3.0f * t3 - 6.0f * t2 + 4.0f) * (1.0f / 6.0f));
      r2 = f2b((-3.0f * t3 + 3.0f * t2 + 3.0f * t_ + 1.0f) * (1.0f / 6.0f));
      r3 = f2b(t3 * (1.0f / 6.0f));
    } else {
      mc = 1 << 20;  // sentinel: no column ever matches
    }
    uintx4 e;
    e.x = (u32)r0 | ((u32)r1 << 16);
    e.y = (u32)r2 | ((u32)r3 << 16);
    e.z = (u32)mc;
    e.w = 0;
    PB[id] = e;
  } else {
    int id = (blk - 2048) * 256 + t;         // 65536 words = 256KB scanned
    u32 w = maskw[id];
    if (w == 0x3F800000u) atomicOr(flags, 2);
    else if (w & 0xFFFFFF00u) atomicOr(flags, 1);
  }
}

// ---- pack B: [o][k] bf16 rows, LDS-staged coalesced in and out
__global__ __launch_bounds__(256) void pack_b_kernel(
    const float* __restrict__ bw, const float* __restrict__ sw,
    const float* __restrict__ sc, const void* __restrict__ maskp,
    const int* __restrict__ flags, u16* __restrict__ B, float* __restrict__ bias) {
  __shared__ u64 lds64[1120 * 4];  // 35840B: float stage, reused as u16 rows
  float* lds_f = (float*)lds64;
  u16* lds_u = (u16*)lds64;

  int t = threadIdx.x, blk = blockIdx.x;
  int id = blk * 256 + t;            // o*512+i
  int o = id >> 9, i = id & 511;
  int i0 = (blk & 1) * 256;

  const float* swb = sw + ((size_t)o * 512 + i0) * 35;
#pragma unroll
  for (int j = 0; j < 35; ++j) lds_f[j * 256 + t] = swb[j * 256 + t];

  int fl = *flags;
  bool mk;
  if (fl & 2)      mk = ((const float*)maskp)[id] != 0.0f;
  else if (fl & 1) mk = ((const unsigned char*)maskp)[id] != 0;
  else             mk = ((const int*)maskp)[id] != 0;

  float s = sc[id];
  __syncthreads();
  float w[35];
#pragma unroll
  for (int c = 0; c < 35; ++c) w[c] = lds_f[t * 35 + c] * s;
  __syncthreads();

  // linear fallback params from endpoint spline values (dx = 2 exactly)
  float ys = (w[0] + 4.0f * w[1] + w[2]) * (1.0f / 6.0f);
  float ye = (w[32] + 4.0f * w[33] + w[34]) * (1.0f / 6.0f);
  float a = (ye - ys) * 0.5f;
  float bl = ys + a;

#pragma unroll
  for (int c = 0; c < 35; ++c) lds_u[t * 36 + c] = f2b(mk ? 0.0f : w[c]);
  lds_u[t * 36 + 35] = 0;

  B[(size_t)o * K_TOT + K_BASE_OFF + i] = f2b(bw[id]);
  B[(size_t)o * K_TOT + K_LIN_OFF + i] = f2b(mk ? a : 0.0f);
  if (mk) atomicAdd(&bias[o], bl);
  __syncthreads();

  u64* dst = (u64*)(B + (size_t)o * K_TOT + (size_t)i0 * 36);
#pragma unroll
  for (int j = 0; j < 9; ++j) dst[j * 256 + t] = lds64[j * 256 + t];
}

// ---- fused GEMM: A-tile built in LDS from PB (spline) or x (silu/linear),
// thread-owned half-rows (no zero/scatter barrier), B via global_load_lds,
// 128x128 tile, BK=64, 16x16x32 bf16 MFMA, 2 barriers/iter.
// grid 608: ks = id/32 (0..18), tile = id%32, bm = tile>>2, bn = tile&3.
__global__ __launch_bounds__(256, 4) void gemm_fused(const float* __restrict__ x,
                                                     const uintx4* __restrict__ PB,
                                                     const u16* __restrict__ Bp,
                                                     u16* __restrict__ P) {
  __shared__ u16 As[128 * 64 + 64];  // +64 u16 dummy pad for dead scatter lanes
  __shared__ u16 Bs[128 * 64];

  int t = threadIdx.x;
  int id = blockIdx.x;
  int ks = id >> 5, tile = id & 31;
  int bm = tile >> 2, bn = tile & 3;
  int w = t >> 6, l = t & 63;
  int wm = w & 1, wn = w >> 1;

  floatx4 acc[4][4];
#pragma unroll
  for (int p = 0; p < 4; ++p)
#pragma unroll
    for (int q = 0; q < 4; ++q) acc[p][q] = (floatx4)0.0f;

  int k0s = ks * KPS;
  bool spline = (ks < 18);

  // B staging params (XOR-swizzled chunks, wave-uniform-base + lane*16 dest)
  int ra = t >> 3;
  int cg = (t & 7) ^ (ra & 7);
  const u16* Bg = Bp + (size_t)(bn * 128 + ra) * K_TOT + k0s + cg * 8;
  u16* Bsp = Bs + t * 8;

  // A-build ownership: row r, col half hf (32 cols)
  int rr_ = t >> 1, hf = t & 1;
  int rx7 = rr_ & 7;
  int dummy = 128 * 64 + (t & 63);

  int mr = l & 15;
  int cq = l >> 4;

  for (int kk = 0; kk < KIT; ++kk) {
    // issue B loads first (drain overlaps A-build)
#pragma unroll
    for (int p = 0; p < 4; ++p)
      __builtin_amdgcn_global_load_lds(
          (const __attribute__((address_space(1))) void*)(Bg + (size_t)p * 32 * K_TOT),
          (__attribute__((address_space(3))) void*)(Bsp + p * 2048), 16, 0, 0);
    Bg += 64;

    if (spline) {
      // zero own 32-col half (4 x b128, swizzled chunks)
#pragma unroll
      for (int q = 0; q < 4; ++q) {
        int ch = hf * 4 + q;
        *(uintx4*)&As[rr_ * 64 + ((ch ^ rx7) << 3)] = (uintx4)0u;
      }
      // scatter <=2 PB entries into own half (same thread: no barrier needed)
      int k0 = k0s + kk * 64;
      int k0w = k0 + hf * 32;
      int i_first = k0w / 36;
      int i_last = (k0w + 31) / 36;
#pragma unroll
      for (int ii = 0; ii < 2; ++ii) {
        int i = i_first + ii;
        if (i <= i_last) {
          uintx4 e = PB[(size_t)(i << 10) + bm * 128 + rr_];
          int mc = (int)e.z;
          int cb = i * 36 + mc - 3 - k0;   // local col of j=0 within the 64-window
          u16 bv[4] = {(u16)e.x, (u16)(e.x >> 16), (u16)e.y, (u16)(e.y >> 16)};
#pragma unroll
          for (int j = 0; j < 4; ++j) {
            int c = cb + j;
            bool ok = ((u32)(c - hf * 32) < 32u) && ((u32)(mc - 3 + j) < 35u);
            int addr = ok ? (rr_ * 64 + (((c >> 3) ^ rx7) << 3) + (c & 7)) : dummy;
            As[addr] = bv[j];
          }
        }
      }
    } else {
      // ks==18: kk<8 -> silu(x) cols; kk>=8 -> x cols. Full fill, no zero pass.
      bool isBase = (kk < 8);
      int xb = (kk & 7) * 64;
#pragma unroll
      for (int p = 0; p < 4; ++p) {
        int cid = t + 256 * p;       // (row, chunk)
        int row = cid >> 3, ch = cid & 7;
        const float* xp = &x[(size_t)(bm * 128 + row) * IN_F + xb + ch * 8];
        floatx4 v0 = *(const floatx4*)xp;
        floatx4 v1 = *(const floatx4*)(xp + 4);
        float f[8] = {v0.x, v0.y, v0.z, v0.w, v1.x, v1.y, v1.z, v1.w};
        u16 r[8];
#pragma unroll
        for (int j = 0; j < 8; ++j) {
          float vv = f[j];
          if (isBase) vv = vv / (1.0f + __expf(-vv));
          r[j] = f2b(vv);
        }
        *(short8*)(As + row * 64 + ((ch ^ (row & 7)) << 3)) = *(short8*)r;
      }
    }
    __syncthreads();

    // MFMA phase
#pragma unroll
    for (int h = 0; h < 2; ++h) {
      short8 af[4], bf[4];
      int c = h * 4 + cq;
#pragma unroll
      for (int tm = 0; tm < 4; ++tm) {
        int row = wm * 64 + tm * 16 + mr;
        af[tm] = *(const short8*)&As[row * 64 + ((c ^ (row & 7)) << 3)];
      }
#pragma unroll
      for (int tn = 0; tn < 4; ++tn) {
        int row = wn * 64 + tn * 16 + mr;
        bf[tn] = *(const short8*)&Bs[row * 64 + ((c ^ (row & 7)) << 3)];
      }
#pragma unroll
      for (int tm = 0; tm < 4; ++tm)
#pragma unroll
        for (int tn = 0; tn < 4; ++tn)
          acc[tm][tn] = __builtin_amdgcn_mfma_f32_16x16x32_bf16(af[tm], bf[tn], acc[tm][tn], 0, 0, 0);
    }
    __syncthreads();
  }

  // ---- epilogue: direct coalesced bf16 partial store, fixed per-thread layout.
  u16* Pb = P + ((size_t)tile * SPLITS + ks) * 16384;
#pragma unroll
  for (int q = 0; q < 8; ++q) {
    int tm = q >> 1, tn0 = (q & 1) * 2;
    u16 r[8];
#pragma unroll
    for (int z = 0; z < 4; ++z) r[z] = f2b(acc[tm][tn0][z]);
#pragma unroll
    for (int z = 0; z < 4; ++z) r[4 + z] = f2b(acc[tm][tn0 + 1][z]);
    *(short8*)(Pb + q * 2048 + t * 8) = *(short8*)r;
  }
}

// ---- reduce 19 bf16 partial tiles + bias -> fp32 out (decodes C-layout)
__global__ __launch_bounds__(256) void reduce_kernel(const u16* __restrict__ P,
                                                     const float* __restrict__ bias,
                                                     float* __restrict__ out) {
  int rid = blockIdx.x * 256 + threadIdx.x;  // 65536 = tile*2048 + q*256 + t
  int tile = rid >> 11;
  int rem = rid & 2047;
  int q = rem >> 8, t = rem & 255;
  const u16* base = P + (size_t)tile * SPLITS * 16384 + q * 2048 + t * 8;

  float s[8] = {0, 0, 0, 0, 0, 0, 0, 0};
#pragma unroll
  for (int ks = 0; ks < SPLITS; ++ks) {
    short8 v = *(const short8*)(base + (size_t)ks * 16384);
#pragma unroll
    for (int j = 0; j < 8; ++j) {
      union { u32 u; float f; } cv; cv.u = ((u32)(u16)v[j]) << 16;
      s[j] += cv.f;
    }
  }

  int w = t >> 6, l = t & 63;
  int wm = w & 1, wn = w >> 1;
  int bm = tile >> 2, bn = tile & 3;
  int row0 = bm * 128 + wm * 64 + ((l >> 4) << 2);
  int col0 = bn * 128 + wn * 64 + (l & 15);
  int tm = q >> 1, tn0 = (q & 1) * 2;
#pragma unroll
  for (int j = 0; j < 8; ++j) {
    int tn = tn0 + (j >> 2), rr = j & 3;
    int row = row0 + tm * 16 + rr;
    int col = col0 + tn * 16;
    out[(size_t)row * OUT_F + col] = s[j] + bias[col];
  }
}

extern "C" void kernel_launch(void* const* d_in, const int* in_sizes, int n_in,
                              void* d_out, int out_size, void* d_ws, size_t ws_size,
                              hipStream_t stream) {
  const float* x  = (const float*)d_in[0];
  const float* bw = (const float*)d_in[1];
  const float* sw = (const float*)d_in[2];
  const float* sc = (const float*)d_in[3];
  // d_in[4] = grid: uniform h=1/16 extended knots, constants baked in.
  const void* mask = d_in[5];

  const size_t B_BYTES = (size_t)OUT_F * K_TOT * 2;         // 19,922,944
  const size_t PB_OFF = B_BYTES + 4096;
  const size_t PB_BYTES = (size_t)MN * 16;                  // 8,388,608
  const size_t P_OFF = PB_OFF + PB_BYTES;                   // P: 19,922,944

  char* wsb = (char*)d_ws;
  u16* Bpack = (u16*)wsb;
  float* bias = (float*)(wsb + B_BYTES);
  int* flags = (int*)(wsb + B_BYTES + 2048);
  uintx4* PB = (uintx4*)(wsb + PB_OFF);
  u16* P = (u16*)(wsb + P_OFF);

  hipMemsetAsync(wsb + B_BYTES, 0, 4096, stream);
  pre_kernel<<<2304, 256, 0, stream>>>(x, PB, (const u32*)mask, flags);
  pack_b_kernel<<<1024, 256, 0, stream>>>(bw, sw, sc, mask, flags, Bpack, bias);
  gemm_fused<<<32 * SPLITS, 256, 0, stream>>>(x, PB, Bpack, P);
  reduce_kernel<<<256, 256, 0, stream>>>(P, bias, (float*)d_out);
}